// Round 1
// baseline (2749.375 us; speedup 1.0000x reference)
//
#include <hip/hip_runtime.h>

// Problem constants (match reference)
#define N_USER  500000
#define N_GROUP 100000
#define N_EDGE  5000000
#define DIM     64

// ---------------------------------------------------------------------------
// Kernel 1: degree counts for both endpoints (one thread per edge).
// ---------------------------------------------------------------------------
__global__ void deg_kernel(const int* __restrict__ src,
                           const int* __restrict__ dst,
                           float* __restrict__ deg_src,
                           float* __restrict__ deg_dst) {
    int e = blockIdx.x * blockDim.x + threadIdx.x;
    if (e < N_EDGE) {
        unsafeAtomicAdd(&deg_src[src[e]], 1.0f);
        unsafeAtomicAdd(&deg_dst[dst[e]], 1.0f);
    }
}

// ---------------------------------------------------------------------------
// Kernel 2: rst[dst] += h_user[src]   (one thread per (edge, dim))
// 64 consecutive threads share one edge -> edge index loads broadcast from L1,
// the 64-float row is a coalesced 256B gather and a coalesced 256B atomic row.
// ---------------------------------------------------------------------------
__global__ void scatter_fwd(const int* __restrict__ src,
                            const int* __restrict__ dst,
                            const float* __restrict__ h_user,
                            float* __restrict__ rst) {
    long idx = (long)blockIdx.x * blockDim.x + threadIdx.x;
    if (idx >= (long)N_EDGE * DIM) return;
    int e = (int)(idx >> 6);
    int d = (int)(idx & 63);
    int s = src[e];
    int g = dst[e];
    unsafeAtomicAdd(&rst[(long)g * DIM + d], h_user[(long)s * DIM + d]);
}

// ---------------------------------------------------------------------------
// Kernel 3: x[r][d] *= 1 / max(deg[r], 1)   (NORM_2 = -1 for the back pass,
// and the forward normalization is also 1/deg -> same kernel for both)
// ---------------------------------------------------------------------------
__global__ void norm_kernel(float* __restrict__ x,
                            const float* __restrict__ deg,
                            long total) {
    long idx = (long)blockIdx.x * blockDim.x + threadIdx.x;
    if (idx >= total) return;
    int r = (int)(idx >> 6);
    float dg = deg[r];
    dg = fmaxf(dg, 1.0f);
    x[idx] *= (1.0f / dg);
}

// ---------------------------------------------------------------------------
// Kernel 4: bsrc[src] += rst[dst]   (one thread per (edge, dim))
// ---------------------------------------------------------------------------
__global__ void scatter_bwd(const int* __restrict__ src,
                            const int* __restrict__ dst,
                            const float* __restrict__ rst,
                            float* __restrict__ bsrc) {
    long idx = (long)blockIdx.x * blockDim.x + threadIdx.x;
    if (idx >= (long)N_EDGE * DIM) return;
    int e = (int)(idx >> 6);
    int d = (int)(idx & 63);
    int s = src[e];
    int g = dst[e];
    unsafeAtomicAdd(&bsrc[(long)s * DIM + d], rst[(long)g * DIM + d]);
}

extern "C" void kernel_launch(void* const* d_in, const int* in_sizes, int n_in,
                              void* d_out, int out_size, void* d_ws, size_t ws_size,
                              hipStream_t stream) {
    const float* h_user  = (const float*)d_in[0];
    // h_group (d_in[1]) unused: ALPHA == 0
    const int*   edge_src = (const int*)d_in[2];
    const int*   edge_dst = (const int*)d_in[3];

    float* bsrc = (float*)d_out;                       // [N_USER, DIM]
    float* rst  = bsrc + (size_t)N_USER * DIM;         // [N_GROUP, DIM]

    float* deg_dst = (float*)d_ws;                     // [N_GROUP]
    float* deg_src = deg_dst + N_GROUP;                // [N_USER]

    // Zero accumulators (poison is 0xAA; we need real zeros every call).
    hipMemsetAsync(d_out, 0, (size_t)(N_USER + N_GROUP) * DIM * sizeof(float), stream);
    hipMemsetAsync(d_ws,  0, (size_t)(N_USER + N_GROUP) * sizeof(float), stream);

    const int BLK = 256;

    // Degrees
    deg_kernel<<<(N_EDGE + BLK - 1) / BLK, BLK, 0, stream>>>(
        edge_src, edge_dst, deg_src, deg_dst);

    // Forward scatter + normalize
    long total_ed = (long)N_EDGE * DIM;
    int grid_ed = (int)((total_ed + BLK - 1) / BLK);
    scatter_fwd<<<grid_ed, BLK, 0, stream>>>(edge_src, edge_dst, h_user, rst);

    long total_g = (long)N_GROUP * DIM;
    norm_kernel<<<(int)((total_g + BLK - 1) / BLK), BLK, 0, stream>>>(
        rst, deg_dst, total_g);

    // Backward scatter + normalize
    scatter_bwd<<<grid_ed, BLK, 0, stream>>>(edge_src, edge_dst, rst, bsrc);

    long total_u = (long)N_USER * DIM;
    norm_kernel<<<(int)((total_u + BLK - 1) / BLK), BLK, 0, stream>>>(
        bsrc, deg_src, total_u);
}

// Round 2
// 1849.482 us; speedup vs baseline: 1.4866x; 1.4866x over previous
//
#include <hip/hip_runtime.h>

// Problem constants (match reference)
#define N_USER  500000
#define N_GROUP 100000
#define N_EDGE  5000000
#define DIM     64

#define SCAN_BLOCK 256
#define SCAN_ELEMS 4096            // elements per scan block (16 per thread)
#define PER_THREAD (SCAN_ELEMS / SCAN_BLOCK)

// ---------------------------------------------------------------------------
// Histogram of both endpoints (int atomics, L2-resident counters).
// ---------------------------------------------------------------------------
__global__ void hist_kernel(const int* __restrict__ src,
                            const int* __restrict__ dst,
                            int* __restrict__ cnt_src,
                            int* __restrict__ cnt_dst) {
    int e = blockIdx.x * blockDim.x + threadIdx.x;
    if (e < N_EDGE) {
        atomicAdd(&cnt_src[src[e]], 1);
        atomicAdd(&cnt_dst[dst[e]], 1);
    }
}

// ---------------------------------------------------------------------------
// Exclusive scan, stage 1: per-block scan of cnt -> off, block totals -> partial.
// ---------------------------------------------------------------------------
__global__ void scan1_kernel(const int* __restrict__ cnt,
                             int* __restrict__ off,
                             int* __restrict__ partial,
                             int n) {
    __shared__ int sh[SCAN_BLOCK];
    int tid = threadIdx.x;
    int base = blockIdx.x * SCAN_ELEMS;
    int tbase = base + tid * PER_THREAD;

    int local[PER_THREAD];
    int sum = 0;
#pragma unroll
    for (int i = 0; i < PER_THREAD; ++i) {
        int idx = tbase + i;
        int v = (idx < n) ? cnt[idx] : 0;
        local[i] = sum;          // exclusive within thread
        sum += v;
    }
    sh[tid] = sum;
    __syncthreads();
    // Hillis-Steele inclusive scan over thread sums
    for (int o = 1; o < SCAN_BLOCK; o <<= 1) {
        int t = (tid >= o) ? sh[tid - o] : 0;
        __syncthreads();
        sh[tid] += t;
        __syncthreads();
    }
    int texc = sh[tid] - sum;    // exclusive offset of this thread in block
    int blockTotal = sh[SCAN_BLOCK - 1];
#pragma unroll
    for (int i = 0; i < PER_THREAD; ++i) {
        int idx = tbase + i;
        if (idx < n) off[idx] = local[i] + texc;
    }
    if (tid == 0) partial[blockIdx.x] = blockTotal;
}

// ---------------------------------------------------------------------------
// Scan stage 2: single-block exclusive scan of <=256 partials; total -> off[n].
// ---------------------------------------------------------------------------
__global__ void scan2_kernel(int* __restrict__ partial, int nb,
                             int* __restrict__ off_end) {
    __shared__ int sh[SCAN_BLOCK];
    int tid = threadIdx.x;
    int v = (tid < nb) ? partial[tid] : 0;
    sh[tid] = v;
    __syncthreads();
    for (int o = 1; o < SCAN_BLOCK; o <<= 1) {
        int t = (tid >= o) ? sh[tid - o] : 0;
        __syncthreads();
        sh[tid] += t;
        __syncthreads();
    }
    if (tid < nb) partial[tid] = sh[tid] - v;   // exclusive
    if (tid == 0) *off_end = sh[SCAN_BLOCK - 1];
}

// ---------------------------------------------------------------------------
// Scan stage 3: add block offsets.
// ---------------------------------------------------------------------------
__global__ void scan3_kernel(int* __restrict__ off,
                             const int* __restrict__ partial, int n) {
    int base = blockIdx.x * SCAN_ELEMS;
    int add = partial[blockIdx.x];
    for (int i = threadIdx.x; i < SCAN_ELEMS; i += blockDim.x) {
        int idx = base + i;
        if (idx < n) off[idx] += add;
    }
}

// ---------------------------------------------------------------------------
// Bucket fill: group edges by key, storing the OTHER endpoint id.
// ---------------------------------------------------------------------------
__global__ void fill_kernel(const int* __restrict__ key,
                            const int* __restrict__ val,
                            const int* __restrict__ off,
                            int* __restrict__ cur,
                            int* __restrict__ bucket) {
    int e = blockIdx.x * blockDim.x + threadIdx.x;
    if (e < N_EDGE) {
        int k = key[e];
        int p = atomicAdd(&cur[k], 1);
        bucket[off[k] + p] = val[e];
    }
}

// ---------------------------------------------------------------------------
// Gather forward: one wave per group; rst[g] = (1/max(deg,1)) * sum h_user[s].
// ---------------------------------------------------------------------------
__global__ void gather_fwd(const int* __restrict__ off,
                           const int* __restrict__ bucket,
                           const float* __restrict__ h_user,
                           float* __restrict__ rst) {
    int wid = (blockIdx.x * blockDim.x + threadIdx.x) >> 6;
    int lane = threadIdx.x & 63;
    if (wid >= N_GROUP) return;
    int beg = off[wid], end = off[wid + 1];
    float acc = 0.0f;
    for (int e = beg; e < end; ++e) {
        int s = bucket[e];
        acc += h_user[(size_t)s * DIM + lane];
    }
    float inv = 1.0f / fmaxf((float)(end - beg), 1.0f);
    rst[(size_t)wid * DIM + lane] = acc * inv;
}

// ---------------------------------------------------------------------------
// Gather backward: one wave per user; bsrc[u] = deg^-1 * sum rst[g].
// ---------------------------------------------------------------------------
__global__ void gather_bwd(const int* __restrict__ off,
                           const int* __restrict__ bucket,
                           const float* __restrict__ rst,
                           float* __restrict__ bsrc) {
    int wid = (blockIdx.x * blockDim.x + threadIdx.x) >> 6;
    int lane = threadIdx.x & 63;
    if (wid >= N_USER) return;
    int beg = off[wid], end = off[wid + 1];
    float acc = 0.0f;
    for (int e = beg; e < end; ++e) {
        int g = bucket[e];
        acc += rst[(size_t)g * DIM + lane];
    }
    float inv = 1.0f / fmaxf((float)(end - beg), 1.0f);
    bsrc[(size_t)wid * DIM + lane] = acc * inv;
}

// ===========================================================================
// Fallback (Round-1 atomic path) if ws_size is too small for CSR scratch.
// ===========================================================================
__global__ void deg_kernel(const int* __restrict__ src,
                           const int* __restrict__ dst,
                           float* __restrict__ deg_src,
                           float* __restrict__ deg_dst) {
    int e = blockIdx.x * blockDim.x + threadIdx.x;
    if (e < N_EDGE) {
        unsafeAtomicAdd(&deg_src[src[e]], 1.0f);
        unsafeAtomicAdd(&deg_dst[dst[e]], 1.0f);
    }
}

__global__ void scatter_fwd(const int* __restrict__ src,
                            const int* __restrict__ dst,
                            const float* __restrict__ h_user,
                            float* __restrict__ rst) {
    long idx = (long)blockIdx.x * blockDim.x + threadIdx.x;
    if (idx >= (long)N_EDGE * DIM) return;
    int e = (int)(idx >> 6), d = (int)(idx & 63);
    unsafeAtomicAdd(&rst[(long)dst[e] * DIM + d], h_user[(long)src[e] * DIM + d]);
}

__global__ void norm_kernel(float* __restrict__ x,
                            const float* __restrict__ deg, long total) {
    long idx = (long)blockIdx.x * blockDim.x + threadIdx.x;
    if (idx >= total) return;
    float dg = fmaxf(deg[idx >> 6], 1.0f);
    x[idx] *= (1.0f / dg);
}

__global__ void scatter_bwd(const int* __restrict__ src,
                            const int* __restrict__ dst,
                            const float* __restrict__ rst,
                            float* __restrict__ bsrc) {
    long idx = (long)blockIdx.x * blockDim.x + threadIdx.x;
    if (idx >= (long)N_EDGE * DIM) return;
    int e = (int)(idx >> 6), d = (int)(idx & 63);
    unsafeAtomicAdd(&bsrc[(long)src[e] * DIM + d], rst[(long)dst[e] * DIM + d]);
}

extern "C" void kernel_launch(void* const* d_in, const int* in_sizes, int n_in,
                              void* d_out, int out_size, void* d_ws, size_t ws_size,
                              hipStream_t stream) {
    const float* h_user   = (const float*)d_in[0];
    const int*   edge_src = (const int*)d_in[2];
    const int*   edge_dst = (const int*)d_in[3];

    float* bsrc = (float*)d_out;                   // [N_USER, DIM]
    float* rst  = bsrc + (size_t)N_USER * DIM;     // [N_GROUP, DIM]

    const int BLK = 256;

    // ---- CSR scratch layout (ints) --------------------------------------
    int* cnt_dst = (int*)d_ws;                     // N_GROUP
    int* off_dst = cnt_dst + N_GROUP;              // N_GROUP + 1
    int* cnt_src = off_dst + N_GROUP + 1;          // N_USER
    int* off_src = cnt_src + N_USER;               // N_USER + 1
    int* cur     = off_src + N_USER + 1;           // N_USER (shared cursor)
    int* partial = cur + N_USER;                   // 256
    int* bucket  = partial + 256;                  // N_EDGE
    size_t needed = (size_t)((bucket + N_EDGE) - (int*)d_ws) * sizeof(int);

    if (ws_size >= needed) {
        // ---- CSR path (no float atomics) --------------------------------
        // Zero cnt_dst..cur (contiguous region before `partial`).
        size_t zero_bytes = (size_t)(partial - cnt_dst) * sizeof(int);
        hipMemsetAsync(d_ws, 0, zero_bytes, stream);

        hist_kernel<<<(N_EDGE + BLK - 1) / BLK, BLK, 0, stream>>>(
            edge_src, edge_dst, cnt_src, cnt_dst);

        // Scan dst degrees -> off_dst
        int nb_dst = (N_GROUP + SCAN_ELEMS - 1) / SCAN_ELEMS;   // 25
        scan1_kernel<<<nb_dst, SCAN_BLOCK, 0, stream>>>(cnt_dst, off_dst, partial, N_GROUP);
        scan2_kernel<<<1, SCAN_BLOCK, 0, stream>>>(partial, nb_dst, off_dst + N_GROUP);
        scan3_kernel<<<nb_dst, SCAN_BLOCK, 0, stream>>>(off_dst, partial, N_GROUP);

        // Scan src degrees -> off_src
        int nb_src = (N_USER + SCAN_ELEMS - 1) / SCAN_ELEMS;    // 123
        scan1_kernel<<<nb_src, SCAN_BLOCK, 0, stream>>>(cnt_src, off_src, partial, N_USER);
        scan2_kernel<<<1, SCAN_BLOCK, 0, stream>>>(partial, nb_src, off_src + N_USER);
        scan3_kernel<<<nb_src, SCAN_BLOCK, 0, stream>>>(off_src, partial, N_USER);

        // Forward: bucket edges by dst (store src), gather into rst.
        fill_kernel<<<(N_EDGE + BLK - 1) / BLK, BLK, 0, stream>>>(
            edge_dst, edge_src, off_dst, cur, bucket);
        gather_fwd<<<(N_GROUP * 64 + BLK - 1) / BLK, BLK, 0, stream>>>(
            off_dst, bucket, h_user, rst);

        // Backward: re-zero cursor, bucket edges by src (store dst), gather.
        hipMemsetAsync(cur, 0, (size_t)N_USER * sizeof(int), stream);
        fill_kernel<<<(N_EDGE + BLK - 1) / BLK, BLK, 0, stream>>>(
            edge_src, edge_dst, off_src, cur, bucket);
        gather_bwd<<<((size_t)N_USER * 64 + BLK - 1) / BLK, BLK, 0, stream>>>(
            off_src, bucket, rst, bsrc);
        return;
    }

    // ---- Fallback: Round-1 atomic path ----------------------------------
    float* deg_dst = (float*)d_ws;
    float* deg_src = deg_dst + N_GROUP;
    hipMemsetAsync(d_out, 0, (size_t)(N_USER + N_GROUP) * DIM * sizeof(float), stream);
    hipMemsetAsync(d_ws, 0, (size_t)(N_USER + N_GROUP) * sizeof(float), stream);

    deg_kernel<<<(N_EDGE + BLK - 1) / BLK, BLK, 0, stream>>>(
        edge_src, edge_dst, deg_src, deg_dst);

    long total_ed = (long)N_EDGE * DIM;
    int grid_ed = (int)((total_ed + BLK - 1) / BLK);
    scatter_fwd<<<grid_ed, BLK, 0, stream>>>(edge_src, edge_dst, h_user, rst);
    long total_g = (long)N_GROUP * DIM;
    norm_kernel<<<(int)((total_g + BLK - 1) / BLK), BLK, 0, stream>>>(rst, deg_dst, total_g);
    scatter_bwd<<<grid_ed, BLK, 0, stream>>>(edge_src, edge_dst, rst, bsrc);
    long total_u = (long)N_USER * DIM;
    norm_kernel<<<(int)((total_u + BLK - 1) / BLK), BLK, 0, stream>>>(bsrc, deg_src, total_u);
}

// Round 3
// 1251.692 us; speedup vs baseline: 2.1965x; 1.4776x over previous
//
#include <hip/hip_runtime.h>

// Problem constants (match reference)
#define N_USER  500000
#define N_GROUP 100000
#define N_EDGE  5000000
#define DIM     64

#define SCAN_BLOCK 256
#define SCAN_ELEMS 4096            // elements per scan block (16 per thread)
#define PER_THREAD (SCAN_ELEMS / SCAN_BLOCK)

// ---------------------------------------------------------------------------
// Histogram of both endpoints (int atomics, L2-resident counters).
// ---------------------------------------------------------------------------
__global__ void hist_kernel(const int* __restrict__ src,
                            const int* __restrict__ dst,
                            int* __restrict__ cnt_src,
                            int* __restrict__ cnt_dst) {
    int e = blockIdx.x * blockDim.x + threadIdx.x;
    if (e < N_EDGE) {
        atomicAdd(&cnt_src[src[e]], 1);
        atomicAdd(&cnt_dst[dst[e]], 1);
    }
}

// ---------------------------------------------------------------------------
// Exclusive scan, stage 1: per-block scan of cnt -> off, block totals -> partial.
// ---------------------------------------------------------------------------
__global__ void scan1_kernel(const int* __restrict__ cnt,
                             int* __restrict__ off,
                             int* __restrict__ partial,
                             int n) {
    __shared__ int sh[SCAN_BLOCK];
    int tid = threadIdx.x;
    int base = blockIdx.x * SCAN_ELEMS;
    int tbase = base + tid * PER_THREAD;

    int local[PER_THREAD];
    int sum = 0;
#pragma unroll
    for (int i = 0; i < PER_THREAD; ++i) {
        int idx = tbase + i;
        int v = (idx < n) ? cnt[idx] : 0;
        local[i] = sum;          // exclusive within thread
        sum += v;
    }
    sh[tid] = sum;
    __syncthreads();
    for (int o = 1; o < SCAN_BLOCK; o <<= 1) {
        int t = (tid >= o) ? sh[tid - o] : 0;
        __syncthreads();
        sh[tid] += t;
        __syncthreads();
    }
    int texc = sh[tid] - sum;
    int blockTotal = sh[SCAN_BLOCK - 1];
#pragma unroll
    for (int i = 0; i < PER_THREAD; ++i) {
        int idx = tbase + i;
        if (idx < n) off[idx] = local[i] + texc;
    }
    if (tid == 0) partial[blockIdx.x] = blockTotal;
}

__global__ void scan2_kernel(int* __restrict__ partial, int nb,
                             int* __restrict__ off_end) {
    __shared__ int sh[SCAN_BLOCK];
    int tid = threadIdx.x;
    int v = (tid < nb) ? partial[tid] : 0;
    sh[tid] = v;
    __syncthreads();
    for (int o = 1; o < SCAN_BLOCK; o <<= 1) {
        int t = (tid >= o) ? sh[tid - o] : 0;
        __syncthreads();
        sh[tid] += t;
        __syncthreads();
    }
    if (tid < nb) partial[tid] = sh[tid] - v;
    if (tid == 0) *off_end = sh[SCAN_BLOCK - 1];
}

__global__ void scan3_kernel(int* __restrict__ off,
                             const int* __restrict__ partial, int n) {
    int base = blockIdx.x * SCAN_ELEMS;
    int add = partial[blockIdx.x];
    for (int i = threadIdx.x; i < SCAN_ELEMS; i += blockDim.x) {
        int idx = base + i;
        if (idx < n) off[idx] += add;
    }
}

// ---------------------------------------------------------------------------
// Fused bucket fill: one edge pass, builds both CSR edge lists.
// ---------------------------------------------------------------------------
__global__ void fill_both(const int* __restrict__ src,
                          const int* __restrict__ dst,
                          const int* __restrict__ off_src,
                          const int* __restrict__ off_dst,
                          int* __restrict__ cur_src,
                          int* __restrict__ cur_dst,
                          int* __restrict__ bucket_src,
                          int* __restrict__ bucket_dst) {
    int e = blockIdx.x * blockDim.x + threadIdx.x;
    if (e < N_EDGE) {
        int u = src[e];
        int g = dst[e];
        int p = atomicAdd(&cur_src[u], 1);
        bucket_src[off_src[u] + p] = g;
        int q = atomicAdd(&cur_dst[g], 1);
        bucket_dst[off_dst[g] + q] = u;
    }
}

// Single-bucket variant (fallback when ws can't fit two buckets).
__global__ void fill_one(const int* __restrict__ key,
                         const int* __restrict__ val,
                         const int* __restrict__ off,
                         int* __restrict__ cur,
                         int* __restrict__ bucket) {
    int e = blockIdx.x * blockDim.x + threadIdx.x;
    if (e < N_EDGE) {
        int k = key[e];
        int p = atomicAdd(&cur[k], 1);
        bucket[off[k] + p] = val[e];
    }
}

// ---------------------------------------------------------------------------
// Gather with 8-deep software pipeline. One wave per output row; lane = dim.
// Main loop: 8 independent row-gathers in flight. Tail: masked 8-wide block
// with indices clamped to end-1 (duplicate loads are L1 hits -> ~free),
// avoiding a serial latency-chained remainder loop.
// NT = nontemporal store for the output (bsrc is never re-read).
// ---------------------------------------------------------------------------
template <int NROW, bool NT>
__global__ void gather_kernel(const int* __restrict__ off,
                              const int* __restrict__ bucket,
                              const float* __restrict__ table,
                              float* __restrict__ out) {
    int wid = (blockIdx.x * blockDim.x + threadIdx.x) >> 6;
    int lane = threadIdx.x & 63;
    if (wid >= NROW) return;
    int beg = off[wid], end = off[wid + 1];

    float a0 = 0, a1 = 0, a2 = 0, a3 = 0, a4 = 0, a5 = 0, a6 = 0, a7 = 0;
    int e = beg;
    for (; e + 8 <= end; e += 8) {
        int s0 = bucket[e + 0], s1 = bucket[e + 1];
        int s2 = bucket[e + 2], s3 = bucket[e + 3];
        int s4 = bucket[e + 4], s5 = bucket[e + 5];
        int s6 = bucket[e + 6], s7 = bucket[e + 7];
        a0 += table[(size_t)s0 * DIM + lane];
        a1 += table[(size_t)s1 * DIM + lane];
        a2 += table[(size_t)s2 * DIM + lane];
        a3 += table[(size_t)s3 * DIM + lane];
        a4 += table[(size_t)s4 * DIM + lane];
        a5 += table[(size_t)s5 * DIM + lane];
        a6 += table[(size_t)s6 * DIM + lane];
        a7 += table[(size_t)s7 * DIM + lane];
    }
    if (e < end) {
        int last = end - 1;
        int i0 = e + 0 < end ? e + 0 : last;
        int i1 = e + 1 < end ? e + 1 : last;
        int i2 = e + 2 < end ? e + 2 : last;
        int i3 = e + 3 < end ? e + 3 : last;
        int i4 = e + 4 < end ? e + 4 : last;
        int i5 = e + 5 < end ? e + 5 : last;
        int i6 = e + 6 < end ? e + 6 : last;
        int i7 = e + 7 < end ? e + 7 : last;
        int s0 = bucket[i0], s1 = bucket[i1], s2 = bucket[i2], s3 = bucket[i3];
        int s4 = bucket[i4], s5 = bucket[i5], s6 = bucket[i6], s7 = bucket[i7];
        float w1 = e + 1 < end ? 1.0f : 0.0f;
        float w2 = e + 2 < end ? 1.0f : 0.0f;
        float w3 = e + 3 < end ? 1.0f : 0.0f;
        float w4 = e + 4 < end ? 1.0f : 0.0f;
        float w5 = e + 5 < end ? 1.0f : 0.0f;
        float w6 = e + 6 < end ? 1.0f : 0.0f;
        float w7 = e + 7 < end ? 1.0f : 0.0f;
        a0 += table[(size_t)s0 * DIM + lane];
        a1 += w1 * table[(size_t)s1 * DIM + lane];
        a2 += w2 * table[(size_t)s2 * DIM + lane];
        a3 += w3 * table[(size_t)s3 * DIM + lane];
        a4 += w4 * table[(size_t)s4 * DIM + lane];
        a5 += w5 * table[(size_t)s5 * DIM + lane];
        a6 += w6 * table[(size_t)s6 * DIM + lane];
        a7 += w7 * table[(size_t)s7 * DIM + lane];
    }
    float acc = ((a0 + a1) + (a2 + a3)) + ((a4 + a5) + (a6 + a7));
    float inv = 1.0f / fmaxf((float)(end - beg), 1.0f);
    float r = acc * inv;
    if (NT) {
        __builtin_nontemporal_store(r, &out[(size_t)wid * DIM + lane]);
    } else {
        out[(size_t)wid * DIM + lane] = r;
    }
}

// ===========================================================================
// Fallback (atomic path) if ws_size is too small for any CSR scratch.
// ===========================================================================
__global__ void deg_kernel(const int* __restrict__ src,
                           const int* __restrict__ dst,
                           float* __restrict__ deg_src,
                           float* __restrict__ deg_dst) {
    int e = blockIdx.x * blockDim.x + threadIdx.x;
    if (e < N_EDGE) {
        unsafeAtomicAdd(&deg_src[src[e]], 1.0f);
        unsafeAtomicAdd(&deg_dst[dst[e]], 1.0f);
    }
}

__global__ void scatter_fwd(const int* __restrict__ src,
                            const int* __restrict__ dst,
                            const float* __restrict__ h_user,
                            float* __restrict__ rst) {
    long idx = (long)blockIdx.x * blockDim.x + threadIdx.x;
    if (idx >= (long)N_EDGE * DIM) return;
    int e = (int)(idx >> 6), d = (int)(idx & 63);
    unsafeAtomicAdd(&rst[(long)dst[e] * DIM + d], h_user[(long)src[e] * DIM + d]);
}

__global__ void norm_kernel(float* __restrict__ x,
                            const float* __restrict__ deg, long total) {
    long idx = (long)blockIdx.x * blockDim.x + threadIdx.x;
    if (idx >= total) return;
    float dg = fmaxf(deg[idx >> 6], 1.0f);
    x[idx] *= (1.0f / dg);
}

__global__ void scatter_bwd(const int* __restrict__ src,
                            const int* __restrict__ dst,
                            const float* __restrict__ rst,
                            float* __restrict__ bsrc) {
    long idx = (long)blockIdx.x * blockDim.x + threadIdx.x;
    if (idx >= (long)N_EDGE * DIM) return;
    int e = (int)(idx >> 6), d = (int)(idx & 63);
    unsafeAtomicAdd(&bsrc[(long)src[e] * DIM + d], rst[(long)dst[e] * DIM + d]);
}

extern "C" void kernel_launch(void* const* d_in, const int* in_sizes, int n_in,
                              void* d_out, int out_size, void* d_ws, size_t ws_size,
                              hipStream_t stream) {
    const float* h_user   = (const float*)d_in[0];
    const int*   edge_src = (const int*)d_in[2];
    const int*   edge_dst = (const int*)d_in[3];

    float* bsrc = (float*)d_out;                   // [N_USER, DIM]
    float* rst  = bsrc + (size_t)N_USER * DIM;     // [N_GROUP, DIM]

    const int BLK = 256;
    const int grid_e = (N_EDGE + BLK - 1) / BLK;

    // ---- scratch layout (ints) ------------------------------------------
    int* ws      = (int*)d_ws;
    int* cnt_dst = ws;                              // N_GROUP
    int* off_dst = cnt_dst + N_GROUP;               // N_GROUP + 1
    int* cnt_src = off_dst + N_GROUP + 1;           // N_USER
    int* off_src = cnt_src + N_USER;                // N_USER + 1
    int* cur_dst = off_src + N_USER + 1;            // N_GROUP
    int* cur_src = cur_dst + N_GROUP;               // N_USER
    int* partial = cur_src + N_USER;                // 256
    int* bucket1 = partial + 256;                   // N_EDGE
    int* bucket2 = bucket1 + N_EDGE;                // N_EDGE (two-bucket path)

    size_t needed2 = (size_t)((bucket2 + N_EDGE) - ws) * sizeof(int);
    size_t needed1 = (size_t)((bucket1 + N_EDGE) - ws) * sizeof(int);

    int nb_dst = (N_GROUP + SCAN_ELEMS - 1) / SCAN_ELEMS;
    int nb_src = (N_USER + SCAN_ELEMS - 1) / SCAN_ELEMS;

    if (ws_size >= needed1) {
        // Zero cnt/cur region (everything before `partial`).
        hipMemsetAsync(d_ws, 0, (size_t)(partial - ws) * sizeof(int), stream);

        hist_kernel<<<grid_e, BLK, 0, stream>>>(edge_src, edge_dst, cnt_src, cnt_dst);

        scan1_kernel<<<nb_dst, SCAN_BLOCK, 0, stream>>>(cnt_dst, off_dst, partial, N_GROUP);
        scan2_kernel<<<1, SCAN_BLOCK, 0, stream>>>(partial, nb_dst, off_dst + N_GROUP);
        scan3_kernel<<<nb_dst, SCAN_BLOCK, 0, stream>>>(off_dst, partial, N_GROUP);

        scan1_kernel<<<nb_src, SCAN_BLOCK, 0, stream>>>(cnt_src, off_src, partial, N_USER);
        scan2_kernel<<<1, SCAN_BLOCK, 0, stream>>>(partial, nb_src, off_src + N_USER);
        scan3_kernel<<<nb_src, SCAN_BLOCK, 0, stream>>>(off_src, partial, N_USER);

        if (ws_size >= needed2) {
            // One edge pass builds both lists.
            fill_both<<<grid_e, BLK, 0, stream>>>(
                edge_src, edge_dst, off_src, off_dst,
                cur_src, cur_dst, bucket2 /*by src -> stores dst*/, bucket1 /*by dst -> stores src*/);

            gather_kernel<N_GROUP, false><<<(N_GROUP * 64 + BLK - 1) / BLK, BLK, 0, stream>>>(
                off_dst, bucket1, h_user, rst);
            gather_kernel<N_USER, true><<<((size_t)N_USER * 64 + BLK - 1) / BLK, BLK, 0, stream>>>(
                off_src, bucket2, rst, bsrc);
        } else {
            // Sequential single-bucket path.
            fill_one<<<grid_e, BLK, 0, stream>>>(edge_dst, edge_src, off_dst, cur_dst, bucket1);
            gather_kernel<N_GROUP, false><<<(N_GROUP * 64 + BLK - 1) / BLK, BLK, 0, stream>>>(
                off_dst, bucket1, h_user, rst);

            fill_one<<<grid_e, BLK, 0, stream>>>(edge_src, edge_dst, off_src, cur_src, bucket1);
            gather_kernel<N_USER, true><<<((size_t)N_USER * 64 + BLK - 1) / BLK, BLK, 0, stream>>>(
                off_src, bucket1, rst, bsrc);
        }
        return;
    }

    // ---- Fallback: atomic path ------------------------------------------
    float* deg_dst = (float*)d_ws;
    float* deg_src = deg_dst + N_GROUP;
    hipMemsetAsync(d_out, 0, (size_t)(N_USER + N_GROUP) * DIM * sizeof(float), stream);
    hipMemsetAsync(d_ws, 0, (size_t)(N_USER + N_GROUP) * sizeof(float), stream);

    deg_kernel<<<grid_e, BLK, 0, stream>>>(edge_src, edge_dst, deg_src, deg_dst);

    long total_ed = (long)N_EDGE * DIM;
    int grid_ed = (int)((total_ed + BLK - 1) / BLK);
    scatter_fwd<<<grid_ed, BLK, 0, stream>>>(edge_src, edge_dst, h_user, rst);
    long total_g = (long)N_GROUP * DIM;
    norm_kernel<<<(int)((total_g + BLK - 1) / BLK), BLK, 0, stream>>>(rst, deg_dst, total_g);
    scatter_bwd<<<grid_ed, BLK, 0, stream>>>(edge_src, edge_dst, rst, bsrc);
    long total_u = (long)N_USER * DIM;
    norm_kernel<<<(int)((total_u + BLK - 1) / BLK), BLK, 0, stream>>>(bsrc, deg_src, total_u);
}